// Round 9
// baseline (110.998 us; speedup 1.0000x reference)
//
#include <hip/hip_runtime.h>
#include <stdint.h>

// DiscreteMarkovDynamics: 5-step Markov jump sim, B=32, L=4096, V=512.
// R1: table precompute + wave-per-position categorical -> 1024 us.
// R2: provable-reject skip (u >= pthr[s] => categorical dead code) -> 250 us.
// R3: split/parallel builds, LDS pthr, PPW=8 -> 125 us.
// R4: fused wide build; ballot candidate scan -> 121 us.
// R5: zoned work-steal REGRESSED (atomics on one cacheline) -> 293 us.
// R6-R8: scheduling variants all plateau at markov ~44-53 us => per-categorical
//     WORK (3.5k cyc) is the lever, not scheduling.
// R9: (a) certified cheap-screen categorical: v_log_f32 screen (|err|<=5e-6,
//     margin EPS=2^-7, 3000x slack) -> exact logf only on ~1.2 shortlisted
//     draws; excluded draws provably below the true max. (b) P-table: accept
//     prob precomputed in build with the identical op chain (bit-equal).
//     (c) screen/jump kernel split: compact candidate-position list, one
//     wave per position chain -> near-perfect balance, no fixed chunk cost.

#define VOCAB  512
#define EMB    256
#define HID    64
#define NPOS   (32 * 4096)   // B*L = 131072
#define STEPS  5
#define JWAVES 8192          // jump kernel grid-stride waves

// Exact mirror of jax._src.prng.threefry2x32 (20 rounds).
__host__ __device__ __forceinline__ void tf2x32(uint32_t k0, uint32_t k1,
                                                uint32_t x0, uint32_t x1,
                                                uint32_t& o0, uint32_t& o1) {
  uint32_t ks2 = k0 ^ k1 ^ 0x1BD11BDAu;
  x0 += k0; x1 += k1;
#define TFR(r) { x0 += x1; x1 = (x1 << (r)) | (x1 >> (32 - (r))); x1 ^= x0; }
  TFR(13) TFR(15) TFR(26) TFR(6)
  x0 += k1;  x1 += ks2 + 1u;
  TFR(17) TFR(29) TFR(16) TFR(24)
  x0 += ks2; x1 += k0 + 2u;
  TFR(13) TFR(15) TFR(26) TFR(6)
  x0 += k0;  x1 += k1 + 3u;
  TFR(17) TFR(29) TFR(16) TFR(24)
  x0 += k1;  x1 += ks2 + 4u;
  TFR(13) TFR(15) TFR(26) TFR(6)
  x0 += ks2; x1 += k0 + 5u;
#undef TFR
  o0 = x0; o1 = x1;
}

struct Keys {
  uint32_t k1a[STEPS], k1b[STEPS];  // categorical (gumbel) keys per step
  uint32_t k2a[STEPS], k2b[STEPS];  // accept-uniform keys per step
};

// Fused table build (R8's proven math) + P table + counter zero.
// P[s][v] = 1-exp(-(I[s][v])*0.01f) via the EXACT accept-path op chain;
// pthr[s] = max_v P[s][v] (== old 1-exp(-rowmax*0.01f): every op monotone
// under rounding, so max commutes with the chain -- bit-identical).
__global__ __launch_bounds__(512)
void build_table(const float* __restrict__ emb,
                 const float* __restrict__ W1,
                 const float* __restrict__ b1,
                 const float* __restrict__ W2,
                 const float* __restrict__ b2,
                 float* __restrict__ I,
                 float* __restrict__ P,
                 float* __restrict__ pthr,
                 uint32_t* __restrict__ counter) {
  const int s   = blockIdx.x;
  const int tid = threadIdx.x;
  if (s == 0 && tid == 0) *counter = 0u;   // ws is poisoned 0xAA each launch

  __shared__ double part[8][HID];
  __shared__ double hd[HID];
  __shared__ float  redmax[8];

  const int hid = tid & (HID - 1);
  const int kq  = tid >> 6;               // 0..7, k = kq + 8*i
  const float* e = emb + s * EMB;
  double acc = 0.0;
#pragma unroll
  for (int ib = 0; ib < 32; ib += 16) {   // two 16-wide load batches
    float ev[16], wv[16];
#pragma unroll
    for (int i = 0; i < 16; ++i) {
      const int k = kq + 8 * (ib + i);
      ev[i] = e[k];
      wv[i] = W1[k * HID + hid];
    }
#pragma unroll
    for (int i = 0; i < 16; ++i)          // same fp64 order as R4-R8
      acc += (double)ev[i] * (double)wv[i];
  }
  part[kq][hid] = acc;
  __syncthreads();
  if (kq == 0) {
    const double a = ((part[0][hid] + part[1][hid]) + (part[2][hid] + part[3][hid]))
                   + ((part[4][hid] + part[5][hid]) + (part[6][hid] + part[7][hid]));
    const float m = (float)a + b1[hid];
    hd[hid] = (double)(m > 0.0f ? m : 0.0f);   // relu
  }
  __syncthreads();

  double acc2 = 0.0;
#pragma unroll
  for (int kb = 0; kb < HID; kb += 16) {
    float wv[16];
#pragma unroll
    for (int i = 0; i < 16; ++i)
      wv[i] = W2[(kb + i) * VOCAB + tid];
#pragma unroll
    for (int i = 0; i < 16; ++i)
      acc2 += hd[kb + i] * (double)wv[i];
  }
  const float val = (float)acc2 + b2[tid];
  I[s * VOCAB + tid] = val;
  const float z = (-val) * 0.01f;               // accept-path op chain
  const float pv = 1.0f - (float)exp((double)z);
  P[s * VOCAB + tid] = pv;

  float lmax = pv;                         // max over P (order-insensitive)
  for (int off = 32; off > 0; off >>= 1)
    lmax = fmaxf(lmax, __shfl_xor(lmax, off, 64));
  if ((tid & 63) == 0) redmax[tid >> 6] = lmax;
  __syncthreads();
  if (tid == 0) {
    float m = redmax[0];
#pragma unroll
    for (int i = 1; i < 8; ++i) m = fmaxf(m, redmax[i]);
    pthr[s] = m;
  }
}

// B1: one thread per position. 5 candidate tests (u_t < pthr[s]); write
// x_out = s for everyone; compact positions with any candidate into list
// (pos | mask<<20), one block-aggregated global atomic per 512 blocks.
__global__ __launch_bounds__(256)
void screen_kernel(const int* __restrict__ x_in,
                   const float* __restrict__ pthr,
                   int* __restrict__ x_out,
                   uint32_t* __restrict__ counter,
                   uint32_t* __restrict__ list,
                   Keys K) {
  const int pos = blockIdx.x * 256 + threadIdx.x;
  const int s = x_in[pos];
  const float th = pthr[s];
  int mask = 0;
#pragma unroll
  for (int t = 0; t < STEPS; ++t) {
    uint32_t w0, w1;
    tf2x32(K.k2a[t], K.k2b[t], 0u, (uint32_t)pos, w0, w1);
    const float u = __uint_as_float((((w0 ^ w1) >> 9) | 0x3f800000u)) - 1.0f;
    if (u < th) mask |= (1 << t);
  }
  x_out[pos] = s;

  const int lane = threadIdx.x & 63, wv = threadIdx.x >> 6;
  const unsigned long long bal = __ballot(mask != 0);
  __shared__ uint32_t wcnt[4], wbase[4];
  if (lane == 0) wcnt[wv] = (uint32_t)__popcll(bal);
  __syncthreads();
  if (threadIdx.x == 0) {
    const uint32_t tot = wcnt[0] + wcnt[1] + wcnt[2] + wcnt[3];
    uint32_t b = atomicAdd(counter, tot);
    wbase[0] = b; b += wcnt[0];
    wbase[1] = b; b += wcnt[1];
    wbase[2] = b; b += wcnt[2];
    wbase[3] = b;
  }
  __syncthreads();
  if (mask) {
    const uint32_t off = wbase[wv] +
        (uint32_t)__popcll(bal & ((1ull << lane) - 1ull));
    list[off] = (uint32_t)pos | ((uint32_t)mask << 20);
  }
}

// B2: one wave per listed position (grid-stride). Per candidate step:
// cheap-screen categorical + P-table accept. On accept, re-test ALL future
// steps against pthr[s_new] (same semantics as R8's re-ballot).
__global__ __launch_bounds__(128)
void jump_kernel(const int* __restrict__ x_in,
                 const float* __restrict__ I,
                 const float* __restrict__ P,
                 const float* __restrict__ pthr,
                 int* __restrict__ x_out,
                 const uint32_t* __restrict__ counter,
                 const uint32_t* __restrict__ list,
                 Keys K) {
  const int lane = threadIdx.x & 63;
  const int wid  = (blockIdx.x << 1) | (threadIdx.x >> 6);
  const int n = (int)*counter;
  const float TINYF = 1.17549435e-38f;
  const float NEGINF = -__builtin_inff();

  for (int i = wid; i < n; i += JWAVES) {
    const uint32_t e = list[i];
    const int pos = (int)(e & 0xFFFFFu);
    int m = (int)(e >> 20);
    int s = __builtin_amdgcn_readfirstlane(x_in[pos]);

    while (m) {
      const int t = __builtin_ctz(m);
      m &= m - 1;

      // Accept uniform (wave-uniform recompute; bit-identical to screen's).
      uint32_t a0, a1;
      tf2x32(K.k2a[t], K.k2b[t], 0u, (uint32_t)pos, a0, a1);
      const float u = __uint_as_float((((a0 ^ a1) >> 9) | 0x3f800000u)) - 1.0f;

      // ---- Categorical with certified cheap screen ----
      const float* row = I + s * VOCAB;
      float rv[8];
#pragma unroll
      for (int j = 0; j < 8; ++j)
        rv[j] = row[lane + (j << 6)];

      const uint32_t fbase = ((uint32_t)pos << 9) + (uint32_t)lane;
      uint32_t bits[8];
#pragma unroll
      for (int j = 0; j < 8; ++j) {
        uint32_t w0, w1;
        tf2x32(K.k1a[t], K.k1b[t], 0u, fbase + ((uint32_t)j << 6), w0, w1);
        bits[j] = w0 ^ w1;
      }

      // Cheap pass: hardware-log gumbel approx, |gC - g| <= ~5e-6.
      float valC[8];
      float bestC = NEGINF;
#pragma unroll
      for (int j = 0; j < 8; ++j) {
        float ufv = __uint_as_float((bits[j] >> 9) | 0x3f800000u) - 1.0f;
        if (ufv == 0.0f) ufv = TINYF;
        const float gC = -__logf(-__logf(ufv));
        const int v = lane + (j << 6);
        valC[j] = (v == s) ? NEGINF : rv[j] + gC;
        bestC = fmaxf(bestC, valC[j]);
      }
      for (int off = 32; off > 0; off >>= 1)
        bestC = fmaxf(bestC, __shfl_xor(bestC, off, 64));
      const float thresh = bestC - 0.015625f;   // 2*EPS, EPS=2^-7 (3000x slack)

      // Exact pass on the shortlist (~1.2 draws/categorical), byte-identical
      // ops to the reference path.
      float best = NEGINF;
      int bidx = 0x7FFFFFFF;
#pragma unroll
      for (int j = 0; j < 8; ++j) {
        if (valC[j] >= thresh) {
          float ufv = __uint_as_float((bits[j] >> 9) | 0x3f800000u) - 1.0f;
          if (ufv == 0.0f) ufv = TINYF;
          const float g = -logf(-logf(ufv));
          const float val = rv[j] + g;
          const int v = lane + (j << 6);
          if (val > best) { best = val; bidx = v; }  // j asc -> first idx
        }
      }
      for (int off = 32; off > 0; off >>= 1) {
        const float ob = __shfl_xor(best, off, 64);
        const int   oi = __shfl_xor(bidx, off, 64);
        if (ob > best || (ob == best && oi < bidx)) { best = ob; bidx = oi; }
      }
      bidx = __builtin_amdgcn_readfirstlane(bidx);

      const float pacc = P[s * VOCAB + bidx];     // precomputed accept prob
      if (u < pacc) {
        s = bidx;                                  // accept jump
        const float th2 = pthr[s];
        int m2 = 0;
        for (int t2 = t + 1; t2 < STEPS; ++t2) {   // re-test ALL future steps
          uint32_t w0, w1;
          tf2x32(K.k2a[t2], K.k2b[t2], 0u, (uint32_t)pos, w0, w1);
          const float u2 =
              __uint_as_float((((w0 ^ w1) >> 9) | 0x3f800000u)) - 1.0f;
          if (u2 < th2) m2 |= (1 << t2);
        }
        m = m2;
      }
    }
    if (lane == 0) x_out[pos] = s;
  }
}

extern "C" void kernel_launch(void* const* d_in, const int* in_sizes, int n_in,
                              void* d_out, int out_size, void* d_ws, size_t ws_size,
                              hipStream_t stream) {
  const int*   x   = (const int*)d_in[0];
  const float* emb = (const float*)d_in[1];
  const float* W1  = (const float*)d_in[2];
  const float* b1  = (const float*)d_in[3];
  const float* W2  = (const float*)d_in[4];
  const float* b2  = (const float*)d_in[5];
  float*    I       = (float*)d_ws;                   // 1 MiB
  float*    P       = I + VOCAB * VOCAB;              // 1 MiB
  float*    pthr    = P + VOCAB * VOCAB;              // 2 KiB
  uint32_t* counter = (uint32_t*)(pthr + VOCAB);      // 4 B (+pad)
  uint32_t* list    = counter + 32;                   // 512 KiB
  int* out = (int*)d_out;

  // Host-side key derivation (partitionable scheme):
  //   key(42) = (0,42); split -> S_t = tf(key,(0,t)); (k1,k2) = tf(S_t,(0,j))
  Keys K;
  for (int t = 0; t < STEPS; ++t) {
    uint32_t Sa, Sb;
    tf2x32(0u, 42u, 0u, (uint32_t)t, Sa, Sb);
    tf2x32(Sa, Sb, 0u, 0u, K.k1a[t], K.k1b[t]);
    tf2x32(Sa, Sb, 0u, 1u, K.k2a[t], K.k2b[t]);
  }

  build_table<<<VOCAB, 512, 0, stream>>>(emb, W1, b1, W2, b2, I, P, pthr, counter);
  screen_kernel<<<NPOS / 256, 256, 0, stream>>>(x, pthr, out, counter, list, K);
  jump_kernel<<<JWAVES / 2, 128, 0, stream>>>(x, I, P, pthr, out, counter, list, K);
}

// Round 10
// 109.837 us; speedup vs baseline: 1.0106x; 1.0106x over previous
//
#include <hip/hip_runtime.h>
#include <stdint.h>

// DiscreteMarkovDynamics: 5-step Markov jump sim, B=32, L=4096, V=512.
// R1: table precompute + wave-per-position categorical -> 1024 us.
// R2: provable-reject skip (u >= pthr[s] => categorical dead code) -> 250 us.
// R3-R8: parallel build; ballot candidate scan; scheduling experiments ->
//     best = R8: single markov kernel, 2048x256 residency, LDS chunk-pull, 44 us.
// R9: 3-kernel screen/jump split was a WASH (launch gaps + serial per-chain
//     L2 latency ate the categorical savings), but it field-proved two cuts
//     (absmax 0): cheap-screen categorical and P-table accept. Profile also
//     exposed the ~70 us harness floor (268 MB ws re-poison fill at 41 us
//     + restore train) -- outside kernel control.
// R10: R8 scheduling + R9 work cuts in ONE kernel.

#define VOCAB  512
#define EMB    256
#define HID    64
#define NPOS   (32 * 4096)   // B*L = 131072
#define STEPS  5
#define PPW    8             // positions per chunk; PPW*STEPS=40 <= 64 lanes
#define CHUNKS (NPOS / PPW)  // 16384
#define MBLK   2048          // markov blocks; 8 chunks per block
#define CPB    (CHUNKS / MBLK)  // 8

// Exact mirror of jax._src.prng.threefry2x32 (20 rounds).
__host__ __device__ __forceinline__ void tf2x32(uint32_t k0, uint32_t k1,
                                                uint32_t x0, uint32_t x1,
                                                uint32_t& o0, uint32_t& o1) {
  uint32_t ks2 = k0 ^ k1 ^ 0x1BD11BDAu;
  x0 += k0; x1 += k1;
#define TFR(r) { x0 += x1; x1 = (x1 << (r)) | (x1 >> (32 - (r))); x1 ^= x0; }
  TFR(13) TFR(15) TFR(26) TFR(6)
  x0 += k1;  x1 += ks2 + 1u;
  TFR(17) TFR(29) TFR(16) TFR(24)
  x0 += ks2; x1 += k0 + 2u;
  TFR(13) TFR(15) TFR(26) TFR(6)
  x0 += k0;  x1 += k1 + 3u;
  TFR(17) TFR(29) TFR(16) TFR(24)
  x0 += k1;  x1 += ks2 + 4u;
  TFR(13) TFR(15) TFR(26) TFR(6)
  x0 += ks2; x1 += k0 + 5u;
#undef TFR
  o0 = x0; o1 = x1;
}

struct Keys {
  uint32_t k1a[STEPS], k1b[STEPS];  // categorical (gumbel) keys per step
  uint32_t k2a[STEPS], k2b[STEPS];  // accept-uniform keys per step
};

// Fused table build (R9's proven math): I, P = 1-exp(-(I)*0.01f) via the
// EXACT accept-path op chain, pthr[s] = max_v P[s][v] (monotone chain =>
// bit-identical to 1-exp(-rowmax*0.01f); both verified absmax 0).
__global__ __launch_bounds__(512)
void build_table(const float* __restrict__ emb,
                 const float* __restrict__ W1,
                 const float* __restrict__ b1,
                 const float* __restrict__ W2,
                 const float* __restrict__ b2,
                 float* __restrict__ I,
                 float* __restrict__ P,
                 float* __restrict__ pthr) {
  const int s   = blockIdx.x;
  const int tid = threadIdx.x;
  __shared__ double part[8][HID];
  __shared__ double hd[HID];
  __shared__ float  redmax[8];

  const int hid = tid & (HID - 1);
  const int kq  = tid >> 6;               // 0..7, k = kq + 8*i
  const float* e = emb + s * EMB;
  double acc = 0.0;
#pragma unroll
  for (int ib = 0; ib < 32; ib += 16) {   // two 16-wide load batches
    float ev[16], wv[16];
#pragma unroll
    for (int i = 0; i < 16; ++i) {
      const int k = kq + 8 * (ib + i);
      ev[i] = e[k];
      wv[i] = W1[k * HID + hid];
    }
#pragma unroll
    for (int i = 0; i < 16; ++i)          // same fp64 order as R4-R9
      acc += (double)ev[i] * (double)wv[i];
  }
  part[kq][hid] = acc;
  __syncthreads();
  if (kq == 0) {
    const double a = ((part[0][hid] + part[1][hid]) + (part[2][hid] + part[3][hid]))
                   + ((part[4][hid] + part[5][hid]) + (part[6][hid] + part[7][hid]));
    const float m = (float)a + b1[hid];
    hd[hid] = (double)(m > 0.0f ? m : 0.0f);   // relu
  }
  __syncthreads();

  double acc2 = 0.0;
#pragma unroll
  for (int kb = 0; kb < HID; kb += 16) {
    float wv[16];
#pragma unroll
    for (int i = 0; i < 16; ++i)
      wv[i] = W2[(kb + i) * VOCAB + tid];
#pragma unroll
    for (int i = 0; i < 16; ++i)
      acc2 += hd[kb + i] * (double)wv[i];
  }
  const float val = (float)acc2 + b2[tid];
  I[s * VOCAB + tid] = val;
  const float z = (-val) * 0.01f;               // accept-path op chain
  const float pv = 1.0f - (float)exp((double)z);
  P[s * VOCAB + tid] = pv;

  float lmax = pv;                         // max over P (order-insensitive)
  for (int off = 32; off > 0; off >>= 1)
    lmax = fmaxf(lmax, __shfl_xor(lmax, off, 64));
  if ((tid & 63) == 0) redmax[tid >> 6] = lmax;
  __syncthreads();
  if (tid == 0) {
    float m = redmax[0];
#pragma unroll
    for (int i = 1; i < 8; ++i) m = fmaxf(m, redmax[i]);
    pthr[s] = m;
  }
}

// Markov kernel: R8's proven scheduling (2048 blocks x 256 = exact residency,
// LDS chunk-pull balancing) + R9's proven categorical cuts (cheap v_log_f32
// screen with EPS=2^-7 certified margin; P-table accept).
__global__ __launch_bounds__(256)
void markov_kernel(const int* __restrict__ x_in,
                   const float* __restrict__ I,
                   const float* __restrict__ P,
                   const float* __restrict__ pthr,
                   int* __restrict__ x_out,
                   Keys K) {
  __shared__ int next_chunk;
  if (threadIdx.x == 0) next_chunk = 0;
  __syncthreads();

  const int lane = threadIdx.x & 63;
  const int qp = lane / 5;                 // lane q -> (position, step)
  const int qt = lane - qp * 5;
  const float TINYF = 1.17549435e-38f;
  const float NEGINF = -__builtin_inff();

  for (;;) {
    int c = 0;
    if (lane == 0) c = atomicAdd(&next_chunk, 1);   // LDS atomic: cheap
    c = __shfl(c, 0, 64);                            // wave-uniform
    if (c >= CPB) break;
    const int base = (blockIdx.x * CPB + c) * PPW;

    // States (lanes 0..7), then per-position pthr, shfl'd to the test lanes.
    int scur = (lane < PPW) ? x_in[base + lane] : 0;
    const float pv = (lane < PPW) ? pthr[scur] : 0.0f;

    // Accept uniforms: lane q < 40 holds u for (p=q/5, t=q%5).
    float u40 = 0.0f;
    if (lane < PPW * STEPS) {
      uint32_t w0, w1;
      tf2x32(K.k2a[qt], K.k2b[qt], 0u, (uint32_t)(base + qp), w0, w1);
      u40 = __uint_as_float((((w0 ^ w1) >> 9) | 0x3f800000u)) - 1.0f;
    }

    // Candidate mask: u_q < pthr[s_p] (state fixed unless an accept occurs).
    const float pq = __shfl(pv, qp, 64);
    const bool cand = (lane < PPW * STEPS) && (u40 < pq);
    unsigned long long mask = __ballot(cand);

    while (mask) {
      const int q = (int)__builtin_ctzll(mask);   // wave-uniform
      mask &= mask - 1;
      const int p = q / 5;
      const int t = q - p * 5;
      const int s = __builtin_amdgcn_readfirstlane(__shfl(scur, p, 64));

      // ---- Categorical with certified cheap screen (R9-proven) ----
      const float* row = I + s * VOCAB;
      float rv[8];
#pragma unroll
      for (int j = 0; j < 8; ++j)               // prefetch row values (L2)
        rv[j] = row[lane + (j << 6)];

      const uint32_t fbase = ((uint32_t)(base + p) << 9) + (uint32_t)lane;
      uint32_t bits[8];
#pragma unroll
      for (int j = 0; j < 8; ++j) {             // 8 independent threefry
        uint32_t w0, w1;
        tf2x32(K.k1a[t], K.k1b[t], 0u, fbase + ((uint32_t)j << 6), w0, w1);
        bits[j] = w0 ^ w1;
      }

      // Cheap pass: hardware-log gumbel approx, |gC - g| <= ~5e-6.
      float valC[8];
      float bestC = NEGINF;
#pragma unroll
      for (int j = 0; j < 8; ++j) {
        float ufv = __uint_as_float((bits[j] >> 9) | 0x3f800000u) - 1.0f;
        if (ufv == 0.0f) ufv = TINYF;
        const float gC = -__logf(-__logf(ufv));
        const int v = lane + (j << 6);
        valC[j] = (v == s) ? NEGINF : rv[j] + gC;
        bestC = fmaxf(bestC, valC[j]);
      }
      for (int off = 32; off > 0; off >>= 1)
        bestC = fmaxf(bestC, __shfl_xor(bestC, off, 64));
      const float thresh = bestC - 0.015625f;   // 2*EPS, EPS=2^-7, 3000x slack

      // Exact pass on the shortlist (~1.2 draws); byte-identical ref ops.
      float best = NEGINF;
      int bidx = 0x7FFFFFFF;
#pragma unroll
      for (int j = 0; j < 8; ++j) {
        if (valC[j] >= thresh) {
          float ufv = __uint_as_float((bits[j] >> 9) | 0x3f800000u) - 1.0f;
          if (ufv == 0.0f) ufv = TINYF;
          const float g = -logf(-logf(ufv));
          const float val = rv[j] + g;
          const int v = lane + (j << 6);
          if (val > best) { best = val; bidx = v; }  // j asc -> first index
        }
      }
      for (int off = 32; off > 0; off >>= 1) {
        const float ob = __shfl_xor(best, off, 64);
        const int   oi = __shfl_xor(bidx, off, 64);
        if (ob > best || (ob == best && oi < bidx)) { best = ob; bidx = oi; }
      }
      bidx = __builtin_amdgcn_readfirstlane(bidx);

      const float pacc = P[s * VOCAB + bidx];   // P-table accept (R9-proven)
      const float u = __shfl(u40, q, 64);
      if (u < pacc) {
        if (lane == p) scur = bidx;                     // accept jump
        // Re-evaluate this position's FUTURE steps under the new state.
        const unsigned long long fut =
            (((1ull << (p * 5 + 5)) - 1) & ~((1ull << (q + 1)) - 1));
        const float pnew = pthr[bidx];                  // scalar (bidx uniform)
        const unsigned long long nb = __ballot(u40 < pnew) & fut;
        mask = (mask & ~fut) | nb;
      }
    }
    if (lane < PPW) x_out[base + lane] = scur;
  }
}

extern "C" void kernel_launch(void* const* d_in, const int* in_sizes, int n_in,
                              void* d_out, int out_size, void* d_ws, size_t ws_size,
                              hipStream_t stream) {
  const int*   x   = (const int*)d_in[0];
  const float* emb = (const float*)d_in[1];
  const float* W1  = (const float*)d_in[2];
  const float* b1  = (const float*)d_in[3];
  const float* W2  = (const float*)d_in[4];
  const float* b2  = (const float*)d_in[5];
  float* I    = (float*)d_ws;                        // 1 MiB
  float* P    = I + VOCAB * VOCAB;                   // 1 MiB
  float* pthr = P + VOCAB * VOCAB;                   // 2 KiB
  int* out = (int*)d_out;

  // Host-side key derivation (partitionable scheme):
  //   key(42) = (0,42); split -> S_t = tf(key,(0,t)); (k1,k2) = tf(S_t,(0,j))
  Keys K;
  for (int t = 0; t < STEPS; ++t) {
    uint32_t Sa, Sb;
    tf2x32(0u, 42u, 0u, (uint32_t)t, Sa, Sb);
    tf2x32(Sa, Sb, 0u, 0u, K.k1a[t], K.k1b[t]);
    tf2x32(Sa, Sb, 0u, 1u, K.k2a[t], K.k2b[t]);
  }

  build_table<<<VOCAB, 512, 0, stream>>>(emb, W1, b1, W2, b2, I, P, pthr);
  markov_kernel<<<MBLK, 256, 0, stream>>>(x, I, P, pthr, out, K);
}